// Round 1
// baseline (724.027 us; speedup 1.0000x reference)
//
#include <hip/hip_runtime.h>
#include <hip/hip_bf16.h>
#include <math.h>

#define T_TOK 1024
#define DIMM  512      // model dim
#define EDIM  1024     // expert hidden
#define HIDD  256      // micro hidden
#define NEXP  8
#define NMIC  325
#define E16TILES 136   // max expert tiles (16-pair): 2048/16 + 8
#define MTILES  840    // max micro tiles (16-pair)
#define NPAIR_M 8192   // T_TOK * 8

typedef __attribute__((ext_vector_type(8))) short bf16x8;   // 8 bf16 (4 VGPRs)
typedef __attribute__((ext_vector_type(4))) float f32x4;    // 4 fp32 acc

__device__ __forceinline__ float dot4(float4 a, float4 b) {
    return a.x*b.x + a.y*b.y + a.z*b.z + a.w*b.w;
}
__device__ __forceinline__ float gelu_exact(float x) {
    return 0.5f * x * (1.0f + erff(x * 0.70710678118654752f));
}
__device__ __forceinline__ float wave_sum(float v) {
    #pragma unroll
    for (int o = 32; o; o >>= 1) v += __shfl_xor(v, o);
    return v;
}
__device__ __forceinline__ short f2bf(float f) {
    union { __hip_bfloat16 h; short s; } u;
    u.h = __float2bfloat16(f);
    return u.s;
}
__device__ __forceinline__ bf16x8 cvt8(float4 a, float4 b) {
    bf16x8 r;
    r[0]=f2bf(a.x); r[1]=f2bf(a.y); r[2]=f2bf(a.z); r[3]=f2bf(a.w);
    r[4]=f2bf(b.x); r[5]=f2bf(b.y); r[6]=f2bf(b.z); r[7]=f2bf(b.w);
    return r;
}

// ---------------- expert router: softmax over 8, top-2, renorm ----------------
__global__ void k_router(const float* __restrict__ x, const float* __restrict__ rw,
                         const float* __restrict__ rb, int* __restrict__ eidx,
                         float* __restrict__ ew, int* __restrict__ ecnt) {
    int wave = threadIdx.x >> 6, lane = threadIdx.x & 63;
    int t = blockIdx.x * 4 + wave;
    if (t >= T_TOK) return;
    const float* xr = x + (size_t)t * DIMM;
    float xv[8];
    #pragma unroll
    for (int j = 0; j < 8; ++j) xv[j] = xr[lane + 64*j];
    float p[NEXP];
    #pragma unroll
    for (int e = 0; e < NEXP; ++e) {
        const float* wr = rw + (size_t)e * DIMM;
        float a = 0.f;
        #pragma unroll
        for (int j = 0; j < 8; ++j) a += xv[j] * wr[lane + 64*j];
        p[e] = wave_sum(a) + rb[e];
    }
    float m = p[0];
    #pragma unroll
    for (int e = 1; e < NEXP; ++e) m = fmaxf(m, p[e]);
    float Z = 0.f;
    #pragma unroll
    for (int e = 0; e < NEXP; ++e) { p[e] = expf(p[e] - m); Z += p[e]; }
    #pragma unroll
    for (int e = 0; e < NEXP; ++e) p[e] /= Z;
    int i1 = 0; float v1 = p[0];
    #pragma unroll
    for (int e = 1; e < NEXP; ++e) if (p[e] > v1) { v1 = p[e]; i1 = e; }
    int i2 = -1; float v2 = -1.f;
    #pragma unroll
    for (int e = 0; e < NEXP; ++e) if (e != i1 && p[e] > v2) { v2 = p[e]; i2 = e; }
    float s = v1 + v2 + 1e-8f;
    if (lane == 0) {
        eidx[t*2] = i1; eidx[t*2+1] = i2;
        ew[t*2] = v1 / s; ew[t*2+1] = v2 / s;
        atomicAdd(&ecnt[i1], 1); atomicAdd(&ecnt[i2], 1);
    }
}

// ---------------- generic scan + tile builder (1 block, 512 threads) ----------------
__global__ void k_scan(const int* __restrict__ cnt, int n, int pm,
                       int* __restrict__ off, int* __restrict__ cur,
                       int2* __restrict__ tiles, int* __restrict__ ntile) {
    __shared__ int s[512], s2[512];
    int tid = threadIdx.x;
    int v  = (tid < n) ? cnt[tid] : 0;
    int tc = (v + pm - 1) / pm;
    s[tid] = v; s2[tid] = tc;
    __syncthreads();
    for (int d = 1; d < 512; d <<= 1) {
        int a = (tid >= d) ? s[tid-d] : 0;
        int b = (tid >= d) ? s2[tid-d] : 0;
        __syncthreads();
        s[tid] += a; s2[tid] += b;
        __syncthreads();
    }
    int myoff = s[tid] - v, tb = s2[tid] - tc;
    if (tid < n) { off[tid] = myoff; cur[tid] = myoff; }
    if (tid == n-1) off[n] = s[tid];
    if (tid == 511) *ntile = s2[511];
    for (int j = 0; j < tc; ++j) tiles[tb + j] = make_int2(tid, myoff + j*pm);
}

// ---------------- generic scatter (also records owning expert/micro id) ----------------
__global__ void k_scatter(const int* __restrict__ idx, const float* __restrict__ w,
                          int total, int S, int* __restrict__ cur,
                          int* __restrict__ ptok, float* __restrict__ pw,
                          int* __restrict__ pmi) {
    int g = blockIdx.x * blockDim.x + threadIdx.x;
    if (g >= total) return;
    int t = g / S;
    int e = idx[g];
    int pos = atomicAdd(&cur[e], 1);
    ptok[pos] = t; pw[pos] = w[g]; pmi[pos] = e;
}

// ---------------- expert FFN1 (fp32, 16-pair tiles): h = gelu(X @ W1^T + b1) ----------
__global__ __launch_bounds__(256) void k_effn1(
    const float* __restrict__ x, const float* __restrict__ w1, const float* __restrict__ b1,
    const int2* __restrict__ tiles, const int* __restrict__ ntile,
    const int* __restrict__ eoff, const int* __restrict__ ep_tok,
    float* __restrict__ hbuf) {
    if ((int)blockIdx.x >= *ntile) return;
    int2 tl = tiles[blockIdx.x];
    int e = tl.x, pbase = tl.y;
    int m = min(16, eoff[e+1] - pbase);
    __shared__ float4 xs[16][128];
    __shared__ int tok_s[16];
    int tid = threadIdx.x;
    if (tid < 16) tok_s[tid] = ep_tok[pbase + ((tid < m) ? tid : 0)];
    __syncthreads();
    const float4* x4 = (const float4*)x;
    for (int q = tid; q < 16*128; q += 256) {
        int i = q >> 7, k = q & 127;
        xs[i][k] = x4[(size_t)tok_s[i] * 128 + k];
    }
    __syncthreads();
    int c = blockIdx.y * 256 + tid;             // 0..1023
    const float4* wr = (const float4*)(w1 + ((size_t)e * EDIM + c) * DIMM);
    float acc[16];
    #pragma unroll
    for (int i = 0; i < 16; ++i) acc[i] = 0.f;
    for (int kk = 0; kk < 128; ++kk) {
        float4 wv = wr[kk];
        #pragma unroll
        for (int i = 0; i < 16; ++i) acc[i] += dot4(wv, xs[i][kk]);
    }
    float bb = b1[(size_t)e * EDIM + c];
    for (int i = 0; i < m; ++i)
        hbuf[(size_t)(pbase + i) * EDIM + c] = gelu_exact(acc[i] + bb);
}

// ---------------- expert FFN2 (fp32, 16-pair tiles): eo += pw * (H @ W2^T + b2) --------
__global__ __launch_bounds__(256) void k_effn2(
    const float* __restrict__ hbuf, const float* __restrict__ w2, const float* __restrict__ b2,
    const int2* __restrict__ tiles, const int* __restrict__ ntile,
    const int* __restrict__ eoff, const int* __restrict__ ep_tok, const float* __restrict__ ep_w,
    float* __restrict__ eo) {
    if ((int)blockIdx.x >= *ntile) return;
    int2 tl = tiles[blockIdx.x];
    int e = tl.x, pbase = tl.y;
    int m = min(16, eoff[e+1] - pbase);
    int kc = blockIdx.z;                         // k-half of 1024
    __shared__ float4 hs[16][128];
    __shared__ int tok_s[16];
    __shared__ float pw_s[16];
    int tid = threadIdx.x;
    if (tid < 16) {
        int ok = tid < m;
        tok_s[tid] = ok ? ep_tok[pbase + tid] : 0;
        pw_s[tid]  = ok ? ep_w[pbase + tid] : 0.f;
    }
    __syncthreads();
    const float4* h4 = (const float4*)hbuf;
    for (int q = tid; q < 16*128; q += 256) {
        int i = q >> 7, k = q & 127;
        hs[i][k] = h4[(size_t)(pbase + ((i < m) ? i : 0)) * 256 + kc * 128 + k];
    }
    __syncthreads();
    int c = blockIdx.y * 256 + tid;              // 0..511
    const float4* wr = (const float4*)(w2 + ((size_t)e * DIMM + c) * EDIM + (size_t)kc * 512);
    float acc[16];
    #pragma unroll
    for (int i = 0; i < 16; ++i) acc[i] = 0.f;
    for (int kk = 0; kk < 128; ++kk) {
        float4 wv = wr[kk];
        #pragma unroll
        for (int i = 0; i < 16; ++i) acc[i] += dot4(wv, hs[i][kk]);
    }
    float bb = (kc == 0) ? b2[(size_t)e * DIMM + c] : 0.f;
    for (int i = 0; i < m; ++i) {
        float val = (acc[i] + bb) * pw_s[i];
        atomicAdd(&eo[(size_t)tok_s[i] * DIMM + c], val);
    }
}

// ---------------- micro router logits: mlog = eo @ mrw^T + mrb (4 tokens/block) -------
__global__ __launch_bounds__(384) void k_mlog(
    const float* __restrict__ eo, const float* __restrict__ mw, const float* __restrict__ mb,
    float* __restrict__ mlog) {
    int t0 = blockIdx.x * 4;
    __shared__ float4 es[4][128];
    int tid = threadIdx.x;
    const float4* eo4 = (const float4*)eo;
    for (int q = tid; q < 4*128; q += 384) {
        int i = q >> 7, k = q & 127;
        es[i][k] = eo4[(size_t)(t0 + i) * 128 + k];
    }
    __syncthreads();
    if (tid < NMIC) {
        const float4* wr = (const float4*)(mw + (size_t)tid * DIMM);
        float acc[4] = {0.f, 0.f, 0.f, 0.f};
        for (int kk = 0; kk < 128; ++kk) {
            float4 wv = wr[kk];
            #pragma unroll
            for (int i = 0; i < 4; ++i) acc[i] += dot4(wv, es[i][kk]);
        }
        float bb = mb[tid];
        #pragma unroll
        for (int i = 0; i < 4; ++i) mlog[(size_t)(t0 + i) * NMIC + tid] = acc[i] + bb;
    }
}

// ---------------- micro top-8 softmax + renorm ----------------
__global__ void k_mtop(const float* __restrict__ mlog, int* __restrict__ mtopi,
                       float* __restrict__ mtopp, int* __restrict__ mcnt) {
    int wave = threadIdx.x >> 6, lane = threadIdx.x & 63;
    int t = blockIdx.x * 4 + wave;
    if (t >= T_TOK) return;
    float v[6]; int vi[6];
    #pragma unroll
    for (int j = 0; j < 6; ++j) {
        int n = lane + 64*j;
        vi[j] = n;
        v[j] = (n < NMIC) ? mlog[(size_t)t * NMIC + n] : -1e30f;
    }
    float M = v[0];
    #pragma unroll
    for (int j = 1; j < 6; ++j) M = fmaxf(M, v[j]);
    #pragma unroll
    for (int o = 32; o; o >>= 1) M = fmaxf(M, __shfl_xor(M, o));
    float Z = 0.f;
    #pragma unroll
    for (int j = 0; j < 6; ++j) Z += expf(v[j] - M);
    Z = wave_sum(Z);
    float bk[8]; int bi[8];
    for (int k = 0; k < 8; ++k) {
        float lv = v[0]; int li = vi[0];
        #pragma unroll
        for (int j = 1; j < 6; ++j)
            if (v[j] > lv) { lv = v[j]; li = vi[j]; }
        #pragma unroll
        for (int o = 32; o; o >>= 1) {
            float ov = __shfl_xor(lv, o); int oi = __shfl_xor(li, o);
            if (ov > lv || (ov == lv && oi < li)) { lv = ov; li = oi; }
        }
        bk[k] = expf(lv - M) / Z; bi[k] = li;
        #pragma unroll
        for (int j = 0; j < 6; ++j) if (vi[j] == li) v[j] = -1e30f;
    }
    float s = 0.f;
    #pragma unroll
    for (int k = 0; k < 8; ++k) s += bk[k];
    s += 1e-8f;
    if (lane == 0) {
        for (int k = 0; k < 8; ++k) {
            mtopi[t*8 + k] = bi[k];
            mtopp[t*8 + k] = bk[k] / s;
            atomicAdd(&mcnt[bi[k]], 1);
        }
    }
}

// ---------------- micro FFN1, bf16 MFMA: H-frags -> global ghbuf ----------------
// A-fragment order for (m,k): off = (k>>5)*512 + (((k>>3)&3)*16 + m)*8 + (k&7)
// C/D layout: col = lane&15, row = (lane>>4)*4 + reg   [m89/m91 verified]
// blockIdx.y splits the HID=256 output cols into 2 halves of 128.
__global__ __launch_bounds__(256) void k_mffn1(
    const float* __restrict__ eo, const float* __restrict__ w1, const float* __restrict__ b1,
    const int2* __restrict__ tiles, const int* __restrict__ ntile,
    const int* __restrict__ moff, const int* __restrict__ mp_tok,
    short* __restrict__ ghbuf) {
    if ((int)blockIdx.x >= *ntile) return;
    int2 tl = tiles[blockIdx.x];
    int mi = tl.x, pbase = tl.y;
    int pm = min(16, moff[mi+1] - pbase);
    int by = blockIdx.y;
    __shared__ __align__(16) short eof[8192];   // 16 tok x 512 bf16 A-frags (16KB)
    __shared__ __align__(16) short hf[2048];    // this block's half of H-frags (4KB)
    __shared__ int tok_s[16];
    int tid = threadIdx.x;
    if (tid < 16) tok_s[tid] = mp_tok[pbase + ((tid < pm) ? tid : 0)];
    __syncthreads();
    // ---- stage EO tile -> bf16 A-fragment order ----
    int m0 = tid & 15;
    const float4* eorow = (const float4*)(eo + (size_t)tok_s[m0] * DIMM);
    for (int kk = tid >> 4; kk < 128; kk += 16) {      // kk = k/4
        float4 v = eorow[kk];
        int off = ((kk >> 3) * 512) + ((((kk >> 1) & 3) * 16 + m0) * 8) + ((kk & 1) * 4);
        short4 s4; s4.x = f2bf(v.x); s4.y = f2bf(v.y); s4.z = f2bf(v.z); s4.w = f2bf(v.w);
        *(short4*)(eof + off) = s4;
    }
    __syncthreads();
    int wave = tid >> 6, lane = tid & 63;
    int quad = lane >> 4, lcol = lane & 15;
    f32x4 zero = {0.f, 0.f, 0.f, 0.f};
    f32x4 accA[2];
    accA[0] = zero; accA[1] = zero;
    const float* w1base = w1 + (size_t)mi * HIDD * DIMM;
    for (int ks = 0; ks < 16; ++ks) {
        bf16x8 a = *(bf16x8*)(eof + ks*512 + lane*8);
        int kb = ks*32 + quad*8;
        #pragma unroll
        for (int q = 0; q < 2; ++q) {
            int n = by*128 + wave*32 + q*16 + lcol;
            const float* wp = w1base + (size_t)n * DIMM + kb;
            float4 wa = *(const float4*)wp;
            float4 wb = *(const float4*)(wp + 4);
            accA[q] = __builtin_amdgcn_mfma_f32_16x16x32_bf16(a, cvt8(wa, wb), accA[q], 0, 0, 0);
        }
    }
    // ---- gelu + bias, write H-frags (local half, h' = h - by*128) ----
    #pragma unroll
    for (int q = 0; q < 2; ++q) {
        int hp = wave*32 + q*16 + lcol;                  // local h in [0,128)
        float bb = b1[(size_t)mi * HIDD + by*128 + hp];
        int obase = ((hp >> 5) * 512) + (((hp >> 3) & 3) * 16) * 8 + (hp & 7);
        #pragma unroll
        for (int r = 0; r < 4; ++r) {
            int mm = quad*4 + r;
            hf[obase + mm*8] = f2bf(gelu_exact(accA[q][r] + bb));
        }
    }
    __syncthreads();
    // ---- coalesced copy of this half-frag to global ----
    short* gh = ghbuf + (size_t)blockIdx.x * 4096 + (size_t)by * 2048;
    ((int4*)gh)[tid] = ((const int4*)hf)[tid];          // 256 x 16B = 4KB
}

// ---------------- micro FFN2, bf16 MFMA: Y = H @ W2^T + b2 -> global ybuf -------------
// A-frags read straight from ghbuf (coalesced 16B/lane). No LDS.
// blockIdx.y splits DIM=512 output cols into 2 halves of 256.
__global__ __launch_bounds__(256) void k_mffn2(
    const short* __restrict__ ghbuf, const float* __restrict__ w2, const float* __restrict__ b2,
    const int2* __restrict__ tiles, const int* __restrict__ ntile, const int* __restrict__ moff,
    float* __restrict__ ybuf) {
    if ((int)blockIdx.x >= *ntile) return;
    int2 tl = tiles[blockIdx.x];
    int mi = tl.x, pbase = tl.y;
    int pm = min(16, moff[mi+1] - pbase);
    int by = blockIdx.y;
    int tid = threadIdx.x, wave = tid >> 6, lane = tid & 63;
    int quad = lane >> 4, lcol = lane & 15;
    const short* gh = ghbuf + (size_t)blockIdx.x * 4096;
    f32x4 zero = {0.f, 0.f, 0.f, 0.f};
    f32x4 accB[4];
    #pragma unroll
    for (int q = 0; q < 4; ++q) accB[q] = zero;
    const float* w2base = w2 + (size_t)mi * DIMM * HIDD;
    for (int ks = 0; ks < 8; ++ks) {
        bf16x8 a = *(const bf16x8*)(gh + ks*512 + lane*8);
        int kb = ks*32 + quad*8;
        #pragma unroll
        for (int q = 0; q < 4; ++q) {
            int d = by*256 + wave*64 + q*16 + lcol;
            const float* wp = w2base + (size_t)d * HIDD + kb;
            float4 wa = *(const float4*)wp;
            float4 wb = *(const float4*)(wp + 4);
            accB[q] = __builtin_amdgcn_mfma_f32_16x16x32_bf16(a, cvt8(wa, wb), accB[q], 0, 0, 0);
        }
    }
    // guard mm < pm: padded rows would collide with the next micro's pairs in ybuf
    #pragma unroll
    for (int q = 0; q < 4; ++q) {
        int d = by*256 + wave*64 + q*16 + lcol;
        float bb = b2[(size_t)mi * DIMM + d];
        #pragma unroll
        for (int r = 0; r < 4; ++r) {
            int mm = quad*4 + r;
            if (mm < pm) ybuf[(size_t)(pbase + mm) * DIMM + d] = accB[q][r] + bb;
        }
    }
}

// ---------------- per-pair LayerNorm(eo + Y), weighted accumulate into mo -------------
__global__ __launch_bounds__(256) void k_mln(
    const float* __restrict__ ybuf, const float* __restrict__ eo,
    const float* __restrict__ g, const float* __restrict__ beta,
    const int* __restrict__ mp_tok, const float* __restrict__ mp_w,
    const int* __restrict__ mp_mi, float* __restrict__ mo) {
    int wave = threadIdx.x >> 6, lane = threadIdx.x & 63;
    int p = blockIdx.x * 4 + wave;                 // total pairs = 8192 exactly
    int t = mp_tok[p];
    int mi = mp_mi[p];
    float pw = mp_w[p];
    const float* yr = ybuf + (size_t)p * DIMM;
    const float* er = eo + (size_t)t * DIMM;
    float vv[8];
    float sum = 0.f;
    #pragma unroll
    for (int j = 0; j < 8; ++j) {
        int d = lane + 64*j;
        vv[j] = yr[d] + er[d];
        sum += vv[j];
    }
    sum = wave_sum(sum);
    float mu = sum * (1.f/512.f);
    float var = 0.f;
    #pragma unroll
    for (int j = 0; j < 8; ++j) { float d0 = vv[j] - mu; var += d0*d0; }
    var = wave_sum(var) * (1.f/512.f);
    float rstd = rsqrtf(var + 1e-5f);
    #pragma unroll
    for (int j = 0; j < 8; ++j) {
        int d = lane + 64*j;
        float nj = (vv[j] - mu) * rstd * g[(size_t)mi * DIMM + d] + beta[(size_t)mi * DIMM + d];
        atomicAdd(&mo[(size_t)t * DIMM + d], pw * nj);
    }
}

// ---------------- final LN over eo + 0.1*mo ----------------
__global__ void k_final(const float* __restrict__ eo, const float* __restrict__ mo,
                        const float* __restrict__ g, const float* __restrict__ b,
                        float* __restrict__ out) {
    int wave = threadIdx.x >> 6, lane = threadIdx.x & 63;
    int t = blockIdx.x * 4 + wave;
    if (t >= T_TOK) return;
    float vv[8];
    float sum = 0.f;
    #pragma unroll
    for (int j = 0; j < 8; ++j) {
        int d = lane + 64*j;
        vv[j] = eo[(size_t)t * DIMM + d] + 0.1f * mo[(size_t)t * DIMM + d];
        sum += vv[j];
    }
    sum = wave_sum(sum);
    float mu = sum * (1.f/512.f);
    float var = 0.f;
    #pragma unroll
    for (int j = 0; j < 8; ++j) { float d0 = vv[j] - mu; var += d0*d0; }
    var = wave_sum(var) * (1.f/512.f);
    float rstd = rsqrtf(var + 1e-5f);
    #pragma unroll
    for (int j = 0; j < 8; ++j) {
        int d = lane + 64*j;
        out[(size_t)t * DIMM + d] = (vv[j] - mu) * rstd * g[d] + b[d];
    }
}

extern "C" void kernel_launch(void* const* d_in, const int* in_sizes, int n_in,
                              void* d_out, int out_size, void* d_ws, size_t ws_size,
                              hipStream_t stream) {
    const float* x    = (const float*)d_in[0];
    const float* rw   = (const float*)d_in[1];
    const float* rb   = (const float*)d_in[2];
    const float* ew1  = (const float*)d_in[3];
    const float* eb1  = (const float*)d_in[4];
    const float* ew2  = (const float*)d_in[5];
    const float* eb2  = (const float*)d_in[6];
    const float* mrw  = (const float*)d_in[7];
    const float* mrb  = (const float*)d_in[8];
    const float* mw1  = (const float*)d_in[9];
    const float* mb1  = (const float*)d_in[10];
    const float* mw2  = (const float*)d_in[11];
    const float* mb2  = (const float*)d_in[12];
    const float* mg   = (const float*)d_in[13];
    const float* mbeta= (const float*)d_in[14];
    const float* ng   = (const float*)d_in[15];
    const float* nb   = (const float*)d_in[16];
    float* out = (float*)d_out;

    char* w = (char*)d_ws;
    auto alloc = [&](size_t bytes) -> char* {
        char* p = w;
        w += (bytes + 255) & ~(size_t)255;
        return p;
    };
    float* eo    = (float*)alloc((size_t)T_TOK * DIMM * 4);   // 2 MB
    float* mo    = (float*)alloc((size_t)T_TOK * DIMM * 4);   // 2 MB (contiguous with eo)
    float* hbuf  = (float*)alloc((size_t)2048 * EDIM * 4);    // 8 MB (ghbuf aliases this later)
    float* ybuf  = (float*)alloc((size_t)NPAIR_M * DIMM * 4); // 16.8 MB
    float* mlog  = (float*)alloc((size_t)T_TOK * NMIC * 4);   // 1.3 MB
    float* ewts  = (float*)alloc(2048 * 4);
    float* mtopp = (float*)alloc(8192 * 4);
    float* ep_w  = (float*)alloc(2048 * 4);
    float* mp_w  = (float*)alloc(8192 * 4);
    int*   eidx  = (int*)alloc(2048 * 4);
    int*   mtopi = (int*)alloc(8192 * 4);
    int*   cnts  = (int*)alloc((NEXP + NMIC) * 4);            // ecnt | mcnt contiguous
    int*   ecnt  = cnts;
    int*   mcnt  = cnts + NEXP;
    int*   eoff  = (int*)alloc((NEXP + 1) * 4);
    int*   ecur  = (int*)alloc(NEXP * 4);
    int*   moff  = (int*)alloc((NMIC + 1) * 4);
    int*   mcur  = (int*)alloc(NMIC * 4);
    int2*  etile = (int2*)alloc(E16TILES * 8);
    int2*  mtile = (int2*)alloc(MTILES * 8);
    int*   entile= (int*)alloc(4);
    int*   mntile= (int*)alloc(4);
    int*   ep_tok= (int*)alloc(2048 * 4);
    int*   mp_tok= (int*)alloc(8192 * 4);
    int*   ep_mi = (int*)alloc(2048 * 4);                     // unused downstream
    int*   mp_mi = (int*)alloc(8192 * 4);
    short* ghbuf = (short*)hbuf;   // 840*4096*2B = 6.9MB <= 8MB; hbuf dead after k_effn2

    hipMemsetAsync(eo, 0, (size_t)2 * T_TOK * DIMM * 4, stream);   // eo + mo
    hipMemsetAsync(cnts, 0, (NEXP + NMIC) * 4, stream);

    k_router <<<T_TOK/4, 256, 0, stream>>>(x, rw, rb, eidx, ewts, ecnt);
    k_scan   <<<1, 512, 0, stream>>>(ecnt, NEXP, 16, eoff, ecur, etile, entile);
    k_scatter<<<(T_TOK*2 + 255)/256, 256, 0, stream>>>(eidx, ewts, T_TOK*2, 2, ecur, ep_tok, ep_w, ep_mi);
    k_effn1  <<<dim3(E16TILES, 4, 1), 256, 0, stream>>>(x, ew1, eb1, etile, entile, eoff, ep_tok, hbuf);
    k_effn2  <<<dim3(E16TILES, 2, 2), 256, 0, stream>>>(hbuf, ew2, eb2, etile, entile, eoff, ep_tok, ep_w, eo);
    k_mlog   <<<T_TOK/4, 384, 0, stream>>>(eo, mrw, mrb, mlog);
    k_mtop   <<<T_TOK/4, 256, 0, stream>>>(mlog, mtopi, mtopp, mcnt);
    k_scan   <<<1, 512, 0, stream>>>(mcnt, NMIC, 16, moff, mcur, mtile, mntile);
    k_scatter<<<(T_TOK*8 + 255)/256, 256, 0, stream>>>(mtopi, mtopp, T_TOK*8, 8, mcur, mp_tok, mp_w, mp_mi);
    k_mffn1  <<<dim3(MTILES, 2, 1), 256, 0, stream>>>(eo, mw1, mb1, mtile, mntile, moff, mp_tok, ghbuf);
    k_mffn2  <<<dim3(MTILES, 2, 1), 256, 0, stream>>>(ghbuf, mw2, mb2, mtile, mntile, moff, ybuf);
    k_mln    <<<NPAIR_M/4, 256, 0, stream>>>(ybuf, eo, mg, mbeta, mp_tok, mp_w, mp_mi, mo);
    k_final  <<<T_TOK/4, 256, 0, stream>>>(eo, mo, ng, nb, out);
}

// Round 2
// 697.863 us; speedup vs baseline: 1.0375x; 1.0375x over previous
//
#include <hip/hip_runtime.h>
#include <hip/hip_bf16.h>
#include <math.h>

#define T_TOK 1024
#define DIMM  512      // model dim
#define EDIM  1024     // expert hidden
#define HIDD  256      // micro hidden
#define NEXP  8
#define NMIC  325
#define E16TILES 136   // max expert tiles (16-pair): 2048/16 + 8
#define MTILES  840    // max micro tiles (16-pair)
#define NPAIR_M 8192   // T_TOK * 8

typedef __attribute__((ext_vector_type(8))) short bf16x8;    // 8 bf16 (4 VGPRs)
typedef __attribute__((ext_vector_type(8))) _Float16 f16x8;  // 8 f16 (4 VGPRs)
typedef __attribute__((ext_vector_type(4))) float f32x4;     // 4 fp32 acc

__device__ __forceinline__ float dot4(float4 a, float4 b) {
    return a.x*b.x + a.y*b.y + a.z*b.z + a.w*b.w;
}
__device__ __forceinline__ float gelu_exact(float x) {
    return 0.5f * x * (1.0f + erff(x * 0.70710678118654752f));
}
__device__ __forceinline__ float wave_sum(float v) {
    #pragma unroll
    for (int o = 32; o; o >>= 1) v += __shfl_xor(v, o);
    return v;
}
__device__ __forceinline__ short f2bf(float f) {
    union { __hip_bfloat16 h; short s; } u;
    u.h = __float2bfloat16(f);
    return u.s;
}
__device__ __forceinline__ short f2h(float f) {
    union { _Float16 h; short s; } u;
    u.h = (_Float16)f;
    return u.s;
}
__device__ __forceinline__ float h2f(short s) {
    union { _Float16 h; short s; } u;
    u.s = s;
    return (float)u.h;
}

// ---------------- expert router: softmax over 8, top-2, renorm ----------------
__global__ void k_router(const float* __restrict__ x, const float* __restrict__ rw,
                         const float* __restrict__ rb, int* __restrict__ eidx,
                         float* __restrict__ ew, int* __restrict__ ecnt) {
    int wave = threadIdx.x >> 6, lane = threadIdx.x & 63;
    int t = blockIdx.x * 4 + wave;
    if (t >= T_TOK) return;
    const float* xr = x + (size_t)t * DIMM;
    float xv[8];
    #pragma unroll
    for (int j = 0; j < 8; ++j) xv[j] = xr[lane + 64*j];
    float p[NEXP];
    #pragma unroll
    for (int e = 0; e < NEXP; ++e) {
        const float* wr = rw + (size_t)e * DIMM;
        float a = 0.f;
        #pragma unroll
        for (int j = 0; j < 8; ++j) a += xv[j] * wr[lane + 64*j];
        p[e] = wave_sum(a) + rb[e];
    }
    float m = p[0];
    #pragma unroll
    for (int e = 1; e < NEXP; ++e) m = fmaxf(m, p[e]);
    float Z = 0.f;
    #pragma unroll
    for (int e = 0; e < NEXP; ++e) { p[e] = expf(p[e] - m); Z += p[e]; }
    #pragma unroll
    for (int e = 0; e < NEXP; ++e) p[e] /= Z;
    int i1 = 0; float v1 = p[0];
    #pragma unroll
    for (int e = 1; e < NEXP; ++e) if (p[e] > v1) { v1 = p[e]; i1 = e; }
    int i2 = -1; float v2 = -1.f;
    #pragma unroll
    for (int e = 0; e < NEXP; ++e) if (e != i1 && p[e] > v2) { v2 = p[e]; i2 = e; }
    float s = v1 + v2 + 1e-8f;
    if (lane == 0) {
        eidx[t*2] = i1; eidx[t*2+1] = i2;
        ew[t*2] = v1 / s; ew[t*2+1] = v2 / s;
        atomicAdd(&ecnt[i1], 1); atomicAdd(&ecnt[i2], 1);
    }
}

// ---------------- generic scan + tile builder (1 block, 512 threads) ----------------
__global__ void k_scan(const int* __restrict__ cnt, int n, int pm,
                       int* __restrict__ off, int* __restrict__ cur,
                       int2* __restrict__ tiles, int* __restrict__ ntile) {
    __shared__ int s[512], s2[512];
    int tid = threadIdx.x;
    int v  = (tid < n) ? cnt[tid] : 0;
    int tc = (v + pm - 1) / pm;
    s[tid] = v; s2[tid] = tc;
    __syncthreads();
    for (int d = 1; d < 512; d <<= 1) {
        int a = (tid >= d) ? s[tid-d] : 0;
        int b = (tid >= d) ? s2[tid-d] : 0;
        __syncthreads();
        s[tid] += a; s2[tid] += b;
        __syncthreads();
    }
    int myoff = s[tid] - v, tb = s2[tid] - tc;
    if (tid < n) { off[tid] = myoff; cur[tid] = myoff; }
    if (tid == n-1) off[n] = s[tid];
    if (tid == 511) *ntile = s2[511];
    for (int j = 0; j < tc; ++j) tiles[tb + j] = make_int2(tid, myoff + j*pm);
}

// ---------------- generic scatter (also records owning expert/micro id) ----------------
__global__ void k_scatter(const int* __restrict__ idx, const float* __restrict__ w,
                          int total, int S, int* __restrict__ cur,
                          int* __restrict__ ptok, float* __restrict__ pw,
                          int* __restrict__ pmi) {
    int g = blockIdx.x * blockDim.x + threadIdx.x;
    if (g >= total) return;
    int t = g / S;
    int e = idx[g];
    int pos = atomicAdd(&cur[e], 1);
    ptok[pos] = t; pw[pos] = w[g]; pmi[pos] = e;
}

// ---------------- W split: w -> f16 hi + f16 lo*4096 (pair keeps ~24 mantissa bits) ---
__global__ __launch_bounds__(256) void k_wsplit(const float* __restrict__ w,
                                                short* __restrict__ hi,
                                                short* __restrict__ lo, int n4) {
    int g = blockIdx.x * blockDim.x + threadIdx.x;
    if (g >= n4) return;
    float4 v = ((const float4*)w)[g];
    short4 h4, l4;
    h4.x = f2h(v.x); l4.x = f2h((v.x - h2f(h4.x)) * 4096.f);
    h4.y = f2h(v.y); l4.y = f2h((v.y - h2f(h4.y)) * 4096.f);
    h4.z = f2h(v.z); l4.z = f2h((v.z - h2f(h4.z)) * 4096.f);
    h4.w = f2h(v.w); l4.w = f2h((v.w - h2f(h4.w)) * 4096.f);
    ((short4*)hi)[g] = h4;
    ((short4*)lo)[g] = l4;
}

// ---------------- expert FFN1, f16-pair MFMA: H-frags -> global ----------------------
// A-fragment order for (m,k): off = (k>>5)*512 + (((k>>3)&3)*16 + m)*8 + (k&7)
// C/D layout: col = lane&15, row = (lane>>4)*4 + reg
// acc0 = xh*wh ; acc1 = xl'*wh + xh*wl' (lo terms pre-scaled by 4096)
// value = acc0 + acc1/4096  (error ~2^-24 rel; keeps micro routing exact)
__global__ __launch_bounds__(256) void k_effn1(
    const float* __restrict__ x, const short* __restrict__ w1h, const short* __restrict__ w1l,
    const float* __restrict__ b1,
    const int2* __restrict__ tiles, const int* __restrict__ ntile,
    const int* __restrict__ eoff, const int* __restrict__ ep_tok,
    short* __restrict__ ghhi, short* __restrict__ ghlo) {
    if ((int)blockIdx.x >= *ntile) return;
    int2 tl = tiles[blockIdx.x];
    int e = tl.x, pbase = tl.y;
    int m = min(16, eoff[e+1] - pbase);
    int by = blockIdx.y;                         // n-half of EDIM
    __shared__ __align__(16) short xh[8192];     // 16 tok x 512 k, f16-hi A-frags (16KB)
    __shared__ __align__(16) short xl[8192];     // f16-lo' A-frags (16KB)
    __shared__ int tok_s[16];
    int tid = threadIdx.x;
    if (tid < 16) tok_s[tid] = ep_tok[pbase + ((tid < m) ? tid : 0)];
    __syncthreads();
    // ---- stage X tile -> f16 hi/lo' A-fragment order ----
    int m0 = tid & 15;
    const float4* xrow = (const float4*)(x + (size_t)tok_s[m0] * DIMM);
    for (int kk = tid >> 4; kk < 128; kk += 16) {      // kk = k/4
        float4 v = xrow[kk];
        int off = ((kk >> 3) * 512) + ((((kk >> 1) & 3) * 16 + m0) * 8) + ((kk & 1) * 4);
        short4 h4, l4;
        h4.x = f2h(v.x); l4.x = f2h((v.x - h2f(h4.x)) * 4096.f);
        h4.y = f2h(v.y); l4.y = f2h((v.y - h2f(h4.y)) * 4096.f);
        h4.z = f2h(v.z); l4.z = f2h((v.z - h2f(h4.z)) * 4096.f);
        h4.w = f2h(v.w); l4.w = f2h((v.w - h2f(h4.w)) * 4096.f);
        *(short4*)(xh + off) = h4;
        *(short4*)(xl + off) = l4;
    }
    __syncthreads();
    int wave = tid >> 6, lane = tid & 63;
    int quad = lane >> 4, lcol = lane & 15;
    f32x4 zero = {0.f, 0.f, 0.f, 0.f};
    f32x4 acc0[8], acc1[8];
    #pragma unroll
    for (int q = 0; q < 8; ++q) { acc0[q] = zero; acc1[q] = zero; }
    const short* w1hb = w1h + (size_t)e * EDIM * DIMM;
    const short* w1lb = w1l + (size_t)e * EDIM * DIMM;
    for (int ks = 0; ks < 16; ++ks) {
        f16x8 ah = *(const f16x8*)(xh + ks*512 + lane*8);
        f16x8 al = *(const f16x8*)(xl + ks*512 + lane*8);
        int kb = ks*32 + quad*8;
        #pragma unroll
        for (int q = 0; q < 8; ++q) {
            int n = by*512 + wave*128 + q*16 + lcol;
            size_t wo = (size_t)n * DIMM + kb;
            f16x8 wh = *(const f16x8*)(w1hb + wo);
            f16x8 wl = *(const f16x8*)(w1lb + wo);
            acc0[q] = __builtin_amdgcn_mfma_f32_16x16x32_f16(ah, wh, acc0[q], 0, 0, 0);
            acc1[q] = __builtin_amdgcn_mfma_f32_16x16x32_f16(al, wh, acc1[q], 0, 0, 0);
            acc1[q] = __builtin_amdgcn_mfma_f32_16x16x32_f16(ah, wl, acc1[q], 0, 0, 0);
        }
    }
    __syncthreads();   // all X-frag reads done; reuse LDS for H-frags
    // ---- gelu + bias, write H as f16 hi/lo' frags (local col hp in [0,512)) ----
    #pragma unroll
    for (int q = 0; q < 8; ++q) {
        int hp = wave*128 + q*16 + lcol;
        float bb = b1[(size_t)e * EDIM + by*512 + hp];
        int obase = ((hp >> 5) * 512) + (((hp >> 3) & 3) * 16) * 8 + (hp & 7);
        #pragma unroll
        for (int r = 0; r < 4; ++r) {
            int mm = quad*4 + r;
            float hv = gelu_exact(acc0[q][r] + acc1[q][r] * (1.f/4096.f) + bb);
            short hh = f2h(hv);
            xh[obase + mm*8] = hh;
            xl[obase + mm*8] = f2h((hv - h2f(hh)) * 4096.f);
        }
    }
    __syncthreads();
    // ---- coalesced copy of this half's frags to global ----
    short* dh = ghhi + (size_t)blockIdx.x * 16384 + (size_t)by * 8192;
    short* dl = ghlo + (size_t)blockIdx.x * 16384 + (size_t)by * 8192;
    const int4* sh = (const int4*)xh;
    const int4* sl = (const int4*)xl;
    #pragma unroll
    for (int j = 0; j < 4; ++j) {                // 16KB / 16B / 256 thr = 4
        ((int4*)dh)[tid + 256*j] = sh[tid + 256*j];
        ((int4*)dl)[tid + 256*j] = sl[tid + 256*j];
    }
}

// ---------------- expert FFN2, f16-pair MFMA: eo += pw * (H @ W2^T + b2) -------------
// A-frags read straight from global (coalesced 16B/lane). No LDS staging.
__global__ __launch_bounds__(256) void k_effn2(
    const short* __restrict__ ghhi, const short* __restrict__ ghlo,
    const short* __restrict__ w2h, const short* __restrict__ w2l, const float* __restrict__ b2,
    const int2* __restrict__ tiles, const int* __restrict__ ntile,
    const int* __restrict__ eoff, const int* __restrict__ ep_tok, const float* __restrict__ ep_w,
    float* __restrict__ eo) {
    if ((int)blockIdx.x >= *ntile) return;
    int2 tl = tiles[blockIdx.x];
    int e = tl.x, pbase = tl.y;
    int m = min(16, eoff[e+1] - pbase);
    int by = blockIdx.y;                         // d-half of DIMM
    __shared__ int tok_s[16];
    __shared__ float pw_s[16];
    int tid = threadIdx.x;
    if (tid < 16) {
        int ok = tid < m;
        tok_s[tid] = ok ? ep_tok[pbase + tid] : 0;
        pw_s[tid]  = ok ? ep_w[pbase + tid] : 0.f;
    }
    __syncthreads();
    int wave = tid >> 6, lane = tid & 63;
    int quad = lane >> 4, lcol = lane & 15;
    const short* ahb = ghhi + (size_t)blockIdx.x * 16384;
    const short* alb = ghlo + (size_t)blockIdx.x * 16384;
    f32x4 zero = {0.f, 0.f, 0.f, 0.f};
    f32x4 acc0[4], acc1[4];
    #pragma unroll
    for (int q = 0; q < 4; ++q) { acc0[q] = zero; acc1[q] = zero; }
    const short* w2hb = w2h + (size_t)e * DIMM * EDIM;
    const short* w2lb = w2l + (size_t)e * DIMM * EDIM;
    for (int ks = 0; ks < 32; ++ks) {            // K = 1024
        f16x8 ah = *(const f16x8*)(ahb + ks*512 + lane*8);
        f16x8 al = *(const f16x8*)(alb + ks*512 + lane*8);
        int kb = ks*32 + quad*8;
        #pragma unroll
        for (int q = 0; q < 4; ++q) {
            int d = by*256 + wave*64 + q*16 + lcol;
            size_t wo = (size_t)d * EDIM + kb;
            f16x8 wh = *(const f16x8*)(w2hb + wo);
            f16x8 wl = *(const f16x8*)(w2lb + wo);
            acc0[q] = __builtin_amdgcn_mfma_f32_16x16x32_f16(ah, wh, acc0[q], 0, 0, 0);
            acc1[q] = __builtin_amdgcn_mfma_f32_16x16x32_f16(al, wh, acc1[q], 0, 0, 0);
            acc1[q] = __builtin_amdgcn_mfma_f32_16x16x32_f16(ah, wl, acc1[q], 0, 0, 0);
        }
    }
    #pragma unroll
    for (int q = 0; q < 4; ++q) {
        int d = by*256 + wave*64 + q*16 + lcol;
        float bb = b2[(size_t)e * DIMM + d];
        #pragma unroll
        for (int r = 0; r < 4; ++r) {
            int mm = quad*4 + r;
            if (mm < m) {
                float val = (acc0[q][r] + acc1[q][r] * (1.f/4096.f) + bb) * pw_s[mm];
                atomicAdd(&eo[(size_t)tok_s[mm] * DIMM + d], val);
            }
        }
    }
}

// ---------------- micro router logits: mlog = eo @ mrw^T + mrb (4 tokens/block) -------
__global__ __launch_bounds__(384) void k_mlog(
    const float* __restrict__ eo, const float* __restrict__ mw, const float* __restrict__ mb,
    float* __restrict__ mlog) {
    int t0 = blockIdx.x * 4;
    __shared__ float4 es[4][128];
    int tid = threadIdx.x;
    const float4* eo4 = (const float4*)eo;
    for (int q = tid; q < 4*128; q += 384) {
        int i = q >> 7, k = q & 127;
        es[i][k] = eo4[(size_t)(t0 + i) * 128 + k];
    }
    __syncthreads();
    if (tid < NMIC) {
        const float4* wr = (const float4*)(mw + (size_t)tid * DIMM);
        float acc[4] = {0.f, 0.f, 0.f, 0.f};
        for (int kk = 0; kk < 128; ++kk) {
            float4 wv = wr[kk];
            #pragma unroll
            for (int i = 0; i < 4; ++i) acc[i] += dot4(wv, es[i][kk]);
        }
        float bb = mb[tid];
        #pragma unroll
        for (int i = 0; i < 4; ++i) mlog[(size_t)(t0 + i) * NMIC + tid] = acc[i] + bb;
    }
}

// ---------------- micro top-8 softmax + renorm ----------------
__global__ void k_mtop(const float* __restrict__ mlog, int* __restrict__ mtopi,
                       float* __restrict__ mtopp, int* __restrict__ mcnt) {
    int wave = threadIdx.x >> 6, lane = threadIdx.x & 63;
    int t = blockIdx.x * 4 + wave;
    if (t >= T_TOK) return;
    float v[6]; int vi[6];
    #pragma unroll
    for (int j = 0; j < 6; ++j) {
        int n = lane + 64*j;
        vi[j] = n;
        v[j] = (n < NMIC) ? mlog[(size_t)t * NMIC + n] : -1e30f;
    }
    float M = v[0];
    #pragma unroll
    for (int j = 1; j < 6; ++j) M = fmaxf(M, v[j]);
    #pragma unroll
    for (int o = 32; o; o >>= 1) M = fmaxf(M, __shfl_xor(M, o));
    float Z = 0.f;
    #pragma unroll
    for (int j = 0; j < 6; ++j) Z += expf(v[j] - M);
    Z = wave_sum(Z);
    float bk[8]; int bi[8];
    for (int k = 0; k < 8; ++k) {
        float lv = v[0]; int li = vi[0];
        #pragma unroll
        for (int j = 1; j < 6; ++j)
            if (v[j] > lv) { lv = v[j]; li = vi[j]; }
        #pragma unroll
        for (int o = 32; o; o >>= 1) {
            float ov = __shfl_xor(lv, o); int oi = __shfl_xor(li, o);
            if (ov > lv || (ov == lv && oi < li)) { lv = ov; li = oi; }
        }
        bk[k] = expf(lv - M) / Z; bi[k] = li;
        #pragma unroll
        for (int j = 0; j < 6; ++j) if (vi[j] == li) v[j] = -1e30f;
    }
    float s = 0.f;
    #pragma unroll
    for (int k = 0; k < 8; ++k) s += bk[k];
    s += 1e-8f;
    if (lane == 0) {
        for (int k = 0; k < 8; ++k) {
            mtopi[t*8 + k] = bi[k];
            mtopp[t*8 + k] = bk[k] / s;
            atomicAdd(&mcnt[bi[k]], 1);
        }
    }
}

// ---------------- micro FFN1, bf16 MFMA: H-frags -> global ghbuf ----------------
__global__ __launch_bounds__(256) void k_mffn1(
    const float* __restrict__ eo, const float* __restrict__ w1, const float* __restrict__ b1,
    const int2* __restrict__ tiles, const int* __restrict__ ntile,
    const int* __restrict__ moff, const int* __restrict__ mp_tok,
    short* __restrict__ ghbuf) {
    if ((int)blockIdx.x >= *ntile) return;
    int2 tl = tiles[blockIdx.x];
    int mi = tl.x, pbase = tl.y;
    int pm = min(16, moff[mi+1] - pbase);
    int by = blockIdx.y;
    __shared__ __align__(16) short eof[8192];   // 16 tok x 512 bf16 A-frags (16KB)
    __shared__ __align__(16) short hf[2048];    // this block's half of H-frags (4KB)
    __shared__ int tok_s[16];
    int tid = threadIdx.x;
    if (tid < 16) tok_s[tid] = mp_tok[pbase + ((tid < pm) ? tid : 0)];
    __syncthreads();
    int m0 = tid & 15;
    const float4* eorow = (const float4*)(eo + (size_t)tok_s[m0] * DIMM);
    for (int kk = tid >> 4; kk < 128; kk += 16) {      // kk = k/4
        float4 v = eorow[kk];
        int off = ((kk >> 3) * 512) + ((((kk >> 1) & 3) * 16 + m0) * 8) + ((kk & 1) * 4);
        short4 s4; s4.x = f2bf(v.x); s4.y = f2bf(v.y); s4.z = f2bf(v.z); s4.w = f2bf(v.w);
        *(short4*)(eof + off) = s4;
    }
    __syncthreads();
    int wave = tid >> 6, lane = tid & 63;
    int quad = lane >> 4, lcol = lane & 15;
    f32x4 zero = {0.f, 0.f, 0.f, 0.f};
    f32x4 accA[2];
    accA[0] = zero; accA[1] = zero;
    const float* w1base = w1 + (size_t)mi * HIDD * DIMM;
    for (int ks = 0; ks < 16; ++ks) {
        bf16x8 a = *(bf16x8*)(eof + ks*512 + lane*8);
        int kb = ks*32 + quad*8;
        #pragma unroll
        for (int q = 0; q < 2; ++q) {
            int n = by*128 + wave*32 + q*16 + lcol;
            const float* wp = w1base + (size_t)n * DIMM + kb;
            float4 wa = *(const float4*)wp;
            float4 wb = *(const float4*)(wp + 4);
            bf16x8 bfr;
            bfr[0]=f2bf(wa.x); bfr[1]=f2bf(wa.y); bfr[2]=f2bf(wa.z); bfr[3]=f2bf(wa.w);
            bfr[4]=f2bf(wb.x); bfr[5]=f2bf(wb.y); bfr[6]=f2bf(wb.z); bfr[7]=f2bf(wb.w);
            accA[q] = __builtin_amdgcn_mfma_f32_16x16x32_bf16(a, bfr, accA[q], 0, 0, 0);
        }
    }
    #pragma unroll
    for (int q = 0; q < 2; ++q) {
        int hp = wave*32 + q*16 + lcol;                  // local h in [0,128)
        float bb = b1[(size_t)mi * HIDD + by*128 + hp];
        int obase = ((hp >> 5) * 512) + (((hp >> 3) & 3) * 16) * 8 + (hp & 7);
        #pragma unroll
        for (int r = 0; r < 4; ++r) {
            int mm = quad*4 + r;
            hf[obase + mm*8] = f2bf(gelu_exact(accA[q][r] + bb));
        }
    }
    __syncthreads();
    short* gh = ghbuf + (size_t)blockIdx.x * 4096 + (size_t)by * 2048;
    ((int4*)gh)[tid] = ((const int4*)hf)[tid];          // 256 x 16B = 4KB
}

// ---------------- micro FFN2, bf16 MFMA: Y = H @ W2^T + b2 -> global ybuf -------------
__global__ __launch_bounds__(256) void k_mffn2(
    const short* __restrict__ ghbuf, const float* __restrict__ w2, const float* __restrict__ b2,
    const int2* __restrict__ tiles, const int* __restrict__ ntile, const int* __restrict__ moff,
    float* __restrict__ ybuf) {
    if ((int)blockIdx.x >= *ntile) return;
    int2 tl = tiles[blockIdx.x];
    int mi = tl.x, pbase = tl.y;
    int pm = min(16, moff[mi+1] - pbase);
    int by = blockIdx.y;
    int tid = threadIdx.x, wave = tid >> 6, lane = tid & 63;
    int quad = lane >> 4, lcol = lane & 15;
    const short* gh = ghbuf + (size_t)blockIdx.x * 4096;
    f32x4 zero = {0.f, 0.f, 0.f, 0.f};
    f32x4 accB[4];
    #pragma unroll
    for (int q = 0; q < 4; ++q) accB[q] = zero;
    const float* w2base = w2 + (size_t)mi * DIMM * HIDD;
    for (int ks = 0; ks < 8; ++ks) {
        bf16x8 a = *(const bf16x8*)(gh + ks*512 + lane*8);
        int kb = ks*32 + quad*8;
        #pragma unroll
        for (int q = 0; q < 4; ++q) {
            int d = by*256 + wave*64 + q*16 + lcol;
            const float* wp = w2base + (size_t)d * HIDD + kb;
            float4 wa = *(const float4*)wp;
            float4 wb = *(const float4*)(wp + 4);
            bf16x8 bfr;
            bfr[0]=f2bf(wa.x); bfr[1]=f2bf(wa.y); bfr[2]=f2bf(wa.z); bfr[3]=f2bf(wa.w);
            bfr[4]=f2bf(wb.x); bfr[5]=f2bf(wb.y); bfr[6]=f2bf(wb.z); bfr[7]=f2bf(wb.w);
            accB[q] = __builtin_amdgcn_mfma_f32_16x16x32_bf16(a, bfr, accB[q], 0, 0, 0);
        }
    }
    #pragma unroll
    for (int q = 0; q < 4; ++q) {
        int d = by*256 + wave*64 + q*16 + lcol;
        float bb = b2[(size_t)mi * DIMM + d];
        #pragma unroll
        for (int r = 0; r < 4; ++r) {
            int mm = quad*4 + r;
            if (mm < pm) ybuf[(size_t)(pbase + mm) * DIMM + d] = accB[q][r] + bb;
        }
    }
}

// ---------------- per-pair LayerNorm(eo + Y), weighted accumulate into mo -------------
__global__ __launch_bounds__(256) void k_mln(
    const float* __restrict__ ybuf, const float* __restrict__ eo,
    const float* __restrict__ g, const float* __restrict__ beta,
    const int* __restrict__ mp_tok, const float* __restrict__ mp_w,
    const int* __restrict__ mp_mi, float* __restrict__ mo) {
    int wave = threadIdx.x >> 6, lane = threadIdx.x & 63;
    int p = blockIdx.x * 4 + wave;                 // total pairs = 8192 exactly
    int t = mp_tok[p];
    int mi = mp_mi[p];
    float pw = mp_w[p];
    const float* yr = ybuf + (size_t)p * DIMM;
    const float* er = eo + (size_t)t * DIMM;
    float vv[8];
    float sum = 0.f;
    #pragma unroll
    for (int j = 0; j < 8; ++j) {
        int d = lane + 64*j;
        vv[j] = yr[d] + er[d];
        sum += vv[j];
    }
    sum = wave_sum(sum);
    float mu = sum * (1.f/512.f);
    float var = 0.f;
    #pragma unroll
    for (int j = 0; j < 8; ++j) { float d0 = vv[j] - mu; var += d0*d0; }
    var = wave_sum(var) * (1.f/512.f);
    float rstd = rsqrtf(var + 1e-5f);
    #pragma unroll
    for (int j = 0; j < 8; ++j) {
        int d = lane + 64*j;
        float nj = (vv[j] - mu) * rstd * g[(size_t)mi * DIMM + d] + beta[(size_t)mi * DIMM + d];
        atomicAdd(&mo[(size_t)t * DIMM + d], pw * nj);
    }
}

// ---------------- final LN over eo + 0.1*mo ----------------
__global__ void k_final(const float* __restrict__ eo, const float* __restrict__ mo,
                        const float* __restrict__ g, const float* __restrict__ b,
                        float* __restrict__ out) {
    int wave = threadIdx.x >> 6, lane = threadIdx.x & 63;
    int t = blockIdx.x * 4 + wave;
    if (t >= T_TOK) return;
    float vv[8];
    float sum = 0.f;
    #pragma unroll
    for (int j = 0; j < 8; ++j) {
        int d = lane + 64*j;
        vv[j] = eo[(size_t)t * DIMM + d] + 0.1f * mo[(size_t)t * DIMM + d];
        sum += vv[j];
    }
    sum = wave_sum(sum);
    float mu = sum * (1.f/512.f);
    float var = 0.f;
    #pragma unroll
    for (int j = 0; j < 8; ++j) { float d0 = vv[j] - mu; var += d0*d0; }
    var = wave_sum(var) * (1.f/512.f);
    float rstd = rsqrtf(var + 1e-5f);
    #pragma unroll
    for (int j = 0; j < 8; ++j) {
        int d = lane + 64*j;
        out[(size_t)t * DIMM + d] = (vv[j] - mu) * rstd * g[d] + b[d];
    }
}

extern "C" void kernel_launch(void* const* d_in, const int* in_sizes, int n_in,
                              void* d_out, int out_size, void* d_ws, size_t ws_size,
                              hipStream_t stream) {
    const float* x    = (const float*)d_in[0];
    const float* rw   = (const float*)d_in[1];
    const float* rb   = (const float*)d_in[2];
    const float* ew1  = (const float*)d_in[3];
    const float* eb1  = (const float*)d_in[4];
    const float* ew2  = (const float*)d_in[5];
    const float* eb2  = (const float*)d_in[6];
    const float* mrw  = (const float*)d_in[7];
    const float* mrb  = (const float*)d_in[8];
    const float* mw1  = (const float*)d_in[9];
    const float* mb1  = (const float*)d_in[10];
    const float* mw2  = (const float*)d_in[11];
    const float* mb2  = (const float*)d_in[12];
    const float* mg   = (const float*)d_in[13];
    const float* mbeta= (const float*)d_in[14];
    const float* ng   = (const float*)d_in[15];
    const float* nb   = (const float*)d_in[16];
    float* out = (float*)d_out;

    char* w = (char*)d_ws;
    auto alloc = [&](size_t bytes) -> char* {
        char* p = w;
        w += (bytes + 255) & ~(size_t)255;
        return p;
    };
    const size_t WELEM = (size_t)NEXP * EDIM * DIMM;          // 4,194,304
    float* eo    = (float*)alloc((size_t)T_TOK * DIMM * 4);   // 2 MB
    float* mo    = (float*)alloc((size_t)T_TOK * DIMM * 4);   // 2 MB (contiguous with eo)
    short* wspl  = (short*)alloc(WELEM * 2 * 4);              // 32 MB: w1h|w1l|w2h|w2l
    short* w1h   = wspl;
    short* w1l   = wspl + WELEM;
    short* w2h   = wspl + 2*WELEM;
    short* w2l   = wspl + 3*WELEM;
    // ybuf aliases w1h|w1l (16 MB): W-split dead after k_effn2, ybuf live mffn2->mln
    float* ybuf  = (float*)wspl;
    short* gfrag = (short*)alloc((size_t)E16TILES * 16384 * 2 * 2);  // 8.9 MB: expert H-frags
    short* ehhi  = gfrag;
    short* ehlo  = gfrag + (size_t)E16TILES * 16384;
    // micro ghbuf aliases gfrag (6.9 MB <= 8.9): expert frags dead after k_effn2
    short* ghbuf = gfrag;
    float* mlog  = (float*)alloc((size_t)T_TOK * NMIC * 4);   // 1.3 MB
    float* ewts  = (float*)alloc(2048 * 4);
    float* mtopp = (float*)alloc(8192 * 4);
    float* ep_w  = (float*)alloc(2048 * 4);
    float* mp_w  = (float*)alloc(8192 * 4);
    int*   eidx  = (int*)alloc(2048 * 4);
    int*   mtopi = (int*)alloc(8192 * 4);
    int*   cnts  = (int*)alloc((NEXP + NMIC) * 4);            // ecnt | mcnt contiguous
    int*   ecnt  = cnts;
    int*   mcnt  = cnts + NEXP;
    int*   eoff  = (int*)alloc((NEXP + 1) * 4);
    int*   ecur  = (int*)alloc(NEXP * 4);
    int*   moff  = (int*)alloc((NMIC + 1) * 4);
    int*   mcur  = (int*)alloc(NMIC * 4);
    int2*  etile = (int2*)alloc(E16TILES * 8);
    int2*  mtile = (int2*)alloc(MTILES * 8);
    int*   entile= (int*)alloc(4);
    int*   mntile= (int*)alloc(4);
    int*   ep_tok= (int*)alloc(2048 * 4);
    int*   mp_tok= (int*)alloc(8192 * 4);
    int*   ep_mi = (int*)alloc(2048 * 4);                     // unused downstream
    int*   mp_mi = (int*)alloc(8192 * 4);

    hipMemsetAsync(eo, 0, (size_t)2 * T_TOK * DIMM * 4, stream);   // eo + mo
    hipMemsetAsync(cnts, 0, (NEXP + NMIC) * 4, stream);

    int n4 = (int)(WELEM / 4);
    k_wsplit <<<n4/256, 256, 0, stream>>>(ew1, w1h, w1l, n4);
    k_wsplit <<<n4/256, 256, 0, stream>>>(ew2, w2h, w2l, n4);
    k_router <<<T_TOK/4, 256, 0, stream>>>(x, rw, rb, eidx, ewts, ecnt);
    k_scan   <<<1, 512, 0, stream>>>(ecnt, NEXP, 16, eoff, ecur, etile, entile);
    k_scatter<<<(T_TOK*2 + 255)/256, 256, 0, stream>>>(eidx, ewts, T_TOK*2, 2, ecur, ep_tok, ep_w, ep_mi);
    k_effn1  <<<dim3(E16TILES, 2, 1), 256, 0, stream>>>(x, w1h, w1l, eb1, etile, entile, eoff, ep_tok, ehhi, ehlo);
    k_effn2  <<<dim3(E16TILES, 2, 1), 256, 0, stream>>>(ehhi, ehlo, w2h, w2l, eb2, etile, entile, eoff, ep_tok, ep_w, eo);
    k_mlog   <<<T_TOK/4, 384, 0, stream>>>(eo, mrw, mrb, mlog);
    k_mtop   <<<T_TOK/4, 256, 0, stream>>>(mlog, mtopi, mtopp, mcnt);
    k_scan   <<<1, 512, 0, stream>>>(mcnt, NMIC, 16, moff, mcur, mtile, mntile);
    k_scatter<<<(T_TOK*8 + 255)/256, 256, 0, stream>>>(mtopi, mtopp, T_TOK*8, 8, mcur, mp_tok, mp_w, mp_mi);
    k_mffn1  <<<dim3(MTILES, 2, 1), 256, 0, stream>>>(eo, mw1, mb1, mtile, mntile, moff, mp_tok, ghbuf);
    k_mffn2  <<<dim3(MTILES, 2, 1), 256, 0, stream>>>(ghbuf, mw2, mb2, mtile, mntile, moff, ybuf);
    k_mln    <<<NPAIR_M/4, 256, 0, stream>>>(ybuf, eo, mg, mbeta, mp_tok, mp_w, mp_mi, mo);
    k_final  <<<T_TOK/4, 256, 0, stream>>>(eo, mo, ng, nb, out);
}

// Round 4
// 680.662 us; speedup vs baseline: 1.0637x; 1.0253x over previous
//
#include <hip/hip_runtime.h>
#include <hip/hip_bf16.h>
#include <math.h>

#define T_TOK 1024
#define DIMM  512      // model dim
#define EDIM  1024     // expert hidden
#define HIDD  256      // micro hidden
#define NEXP  8
#define NMIC  325
#define E16TILES 136   // max expert tiles (16-pair): 2048/16 + 8
#define MTILES  840    // max micro tiles (16-pair)
#define NPAIR_M 8192   // T_TOK * 8

typedef __attribute__((ext_vector_type(8))) short bf16x8;    // 8 bf16 (4 VGPRs)
typedef __attribute__((ext_vector_type(8))) _Float16 f16x8;  // 8 f16 (4 VGPRs)
typedef __attribute__((ext_vector_type(4))) float f32x4;     // 4 fp32 acc

__device__ __forceinline__ float dot4(float4 a, float4 b) {
    return a.x*b.x + a.y*b.y + a.z*b.z + a.w*b.w;
}
__device__ __forceinline__ float gelu_exact(float x) {
    return 0.5f * x * (1.0f + erff(x * 0.70710678118654752f));
}
__device__ __forceinline__ float wave_sum(float v) {
    #pragma unroll
    for (int o = 32; o; o >>= 1) v += __shfl_xor(v, o);
    return v;
}
__device__ __forceinline__ short f2bf(float f) {
    union { __hip_bfloat16 h; short s; } u;
    u.h = __float2bfloat16(f);
    return u.s;
}
__device__ __forceinline__ short f2h(float f) {
    union { _Float16 h; short s; } u;
    u.h = (_Float16)f;
    return u.s;
}
__device__ __forceinline__ float h2f(short s) {
    union { _Float16 h; short s; } u;
    u.s = s;
    return (float)u.h;
}

// ====== weight packers: fp32 [rows][K] -> MFMA B-frag order ======
// frag for (row-tile rt, ks): 512 shorts at ((rt*(K/32)+ks)*512), lane=quad*16+lcol
// holds W[rt*16+lcol][ks*32+quad*8+j].  Chunk = 16 rows x CK cols.
// dst chunk base = rt*16*K + kc*16*CK (contiguous 16*CK shorts).
__global__ __launch_bounds__(256) void k_packbf(const float* __restrict__ src,
                                                short* __restrict__ dst,
                                                int K, int CK, int nchunk) {
    int c = blockIdx.x;
    int rt = c / nchunk, kc = c - rt * nchunk;
    __shared__ __align__(16) short lds[8192];          // up to 16x512
    int tid = threadIdx.x;
    const float4* s4 = (const float4*)(src + (size_t)rt * 16 * K + (size_t)kc * CK);
    int ck4 = CK >> 2;
    int tot = 16 * ck4;
    for (int q = tid; q < tot; q += 256) {
        int i = q / ck4, kk = q - i * ck4;
        float4 v = s4[(size_t)i * (K >> 2) + kk];
        int off = ((kk >> 3) * 512) + ((((kk >> 1) & 3) * 16 + i) * 8) + ((kk & 1) * 4);
        short4 b4; b4.x = f2bf(v.x); b4.y = f2bf(v.y); b4.z = f2bf(v.z); b4.w = f2bf(v.w);
        *(short4*)(lds + off) = b4;
    }
    __syncthreads();
    short* d = dst + (size_t)rt * 16 * K + (size_t)kc * 16 * CK;
    int n16 = (16 * CK) >> 3;                          // int4 count
    for (int q = tid; q < n16; q += 256)
        ((int4*)d)[q] = ((const int4*)lds)[q];
}

// f16 hi/lo pair variant (experts): keeps ~24 mantissa bits across the pair
__global__ __launch_bounds__(256) void k_packhl(const float* __restrict__ src,
                                                short* __restrict__ dsth,
                                                short* __restrict__ dstl,
                                                int K, int CK, int nchunk) {
    int c = blockIdx.x;
    int rt = c / nchunk, kc = c - rt * nchunk;
    __shared__ __align__(16) short ldh[8192];
    __shared__ __align__(16) short ldl[8192];
    int tid = threadIdx.x;
    const float4* s4 = (const float4*)(src + (size_t)rt * 16 * K + (size_t)kc * CK);
    int ck4 = CK >> 2;
    int tot = 16 * ck4;
    for (int q = tid; q < tot; q += 256) {
        int i = q / ck4, kk = q - i * ck4;
        float4 v = s4[(size_t)i * (K >> 2) + kk];
        int off = ((kk >> 3) * 512) + ((((kk >> 1) & 3) * 16 + i) * 8) + ((kk & 1) * 4);
        short4 h4, l4;
        h4.x = f2h(v.x); l4.x = f2h((v.x - h2f(h4.x)) * 4096.f);
        h4.y = f2h(v.y); l4.y = f2h((v.y - h2f(h4.y)) * 4096.f);
        h4.z = f2h(v.z); l4.z = f2h((v.z - h2f(h4.z)) * 4096.f);
        h4.w = f2h(v.w); l4.w = f2h((v.w - h2f(h4.w)) * 4096.f);
        *(short4*)(ldh + off) = h4;
        *(short4*)(ldl + off) = l4;
    }
    __syncthreads();
    size_t cb = (size_t)rt * 16 * K + (size_t)kc * 16 * CK;
    int n16 = (16 * CK) >> 3;
    for (int q = tid; q < n16; q += 256) {
        ((int4*)(dsth + cb))[q] = ((const int4*)ldh)[q];
        ((int4*)(dstl + cb))[q] = ((const int4*)ldl)[q];
    }
}

// ---------------- expert router: softmax over 8, top-2, renorm ----------------
__global__ void k_router(const float* __restrict__ x, const float* __restrict__ rw,
                         const float* __restrict__ rb, int* __restrict__ eidx,
                         float* __restrict__ ew, int* __restrict__ ecnt) {
    int wave = threadIdx.x >> 6, lane = threadIdx.x & 63;
    int t = blockIdx.x * 4 + wave;
    if (t >= T_TOK) return;
    const float* xr = x + (size_t)t * DIMM;
    float xv[8];
    #pragma unroll
    for (int j = 0; j < 8; ++j) xv[j] = xr[lane + 64*j];
    float p[NEXP];
    #pragma unroll
    for (int e = 0; e < NEXP; ++e) {
        const float* wr = rw + (size_t)e * DIMM;
        float a = 0.f;
        #pragma unroll
        for (int j = 0; j < 8; ++j) a += xv[j] * wr[lane + 64*j];
        p[e] = wave_sum(a) + rb[e];
    }
    float m = p[0];
    #pragma unroll
    for (int e = 1; e < NEXP; ++e) m = fmaxf(m, p[e]);
    float Z = 0.f;
    #pragma unroll
    for (int e = 0; e < NEXP; ++e) { p[e] = expf(p[e] - m); Z += p[e]; }
    #pragma unroll
    for (int e = 0; e < NEXP; ++e) p[e] /= Z;
    int i1 = 0; float v1 = p[0];
    #pragma unroll
    for (int e = 1; e < NEXP; ++e) if (p[e] > v1) { v1 = p[e]; i1 = e; }
    int i2 = -1; float v2 = -1.f;
    #pragma unroll
    for (int e = 0; e < NEXP; ++e) if (e != i1 && p[e] > v2) { v2 = p[e]; i2 = e; }
    float s = v1 + v2 + 1e-8f;
    if (lane == 0) {
        eidx[t*2] = i1; eidx[t*2+1] = i2;
        ew[t*2] = v1 / s; ew[t*2+1] = v2 / s;
        atomicAdd(&ecnt[i1], 1); atomicAdd(&ecnt[i2], 1);
    }
}

// ---------------- generic scan + tile builder (1 block, 512 threads) ----------------
__global__ void k_scan(const int* __restrict__ cnt, int n, int pm,
                       int* __restrict__ off, int* __restrict__ cur,
                       int2* __restrict__ tiles, int* __restrict__ ntile) {
    __shared__ int s[512], s2[512];
    int tid = threadIdx.x;
    int v  = (tid < n) ? cnt[tid] : 0;
    int tc = (v + pm - 1) / pm;
    s[tid] = v; s2[tid] = tc;
    __syncthreads();
    for (int d = 1; d < 512; d <<= 1) {
        int a = (tid >= d) ? s[tid-d] : 0;
        int b = (tid >= d) ? s2[tid-d] : 0;
        __syncthreads();
        s[tid] += a; s2[tid] += b;
        __syncthreads();
    }
    int myoff = s[tid] - v, tb = s2[tid] - tc;
    if (tid < n) { off[tid] = myoff; cur[tid] = myoff; }
    if (tid == n-1) off[n] = s[tid];
    if (tid == 511) *ntile = s2[511];
    for (int j = 0; j < tc; ++j) tiles[tb + j] = make_int2(tid, myoff + j*pm);
}

// ---------------- generic scatter (also records owning expert/micro id) ----------------
__global__ void k_scatter(const int* __restrict__ idx, const float* __restrict__ w,
                          int total, int S, int* __restrict__ cur,
                          int* __restrict__ ptok, float* __restrict__ pw,
                          int* __restrict__ pmi) {
    int g = blockIdx.x * blockDim.x + threadIdx.x;
    if (g >= total) return;
    int t = g / S;
    int e = idx[g];
    int pos = atomicAdd(&cur[e], 1);
    ptok[pos] = t; pw[pos] = w[g]; pmi[pos] = e;
}

// ---------------- expert FFN1, f16-pair MFMA, frag-packed W: H-frags -> global --------
// A-fragment order for (m,k): off = (k>>5)*512 + (((k>>3)&3)*16 + m)*8 + (k&7)
// C/D layout: col = lane&15, row = (lane>>4)*4 + reg
// value = acc0 + acc1/4096  (pair split keeps ~24 mantissa bits; routing stays exact)
__global__ __launch_bounds__(256) void k_effn1(
    const float* __restrict__ x, const short* __restrict__ w1h, const short* __restrict__ w1l,
    const float* __restrict__ b1,
    const int2* __restrict__ tiles, const int* __restrict__ ntile,
    const int* __restrict__ eoff, const int* __restrict__ ep_tok,
    short* __restrict__ ghhi, short* __restrict__ ghlo) {
    if ((int)blockIdx.x >= *ntile) return;
    int2 tl = tiles[blockIdx.x];
    int e = tl.x, pbase = tl.y;
    int m = min(16, eoff[e+1] - pbase);
    int by = blockIdx.y;                         // n-half of EDIM
    __shared__ __align__(16) short xh[8192];     // 16 tok x 512 k, f16-hi A-frags (16KB)
    __shared__ __align__(16) short xl[8192];     // f16-lo' A-frags (16KB)
    __shared__ int tok_s[16];
    int tid = threadIdx.x;
    if (tid < 16) tok_s[tid] = ep_tok[pbase + ((tid < m) ? tid : 0)];
    __syncthreads();
    // ---- stage X tile -> f16 hi/lo' A-fragment order ----
    int m0 = tid & 15;
    const float4* xrow = (const float4*)(x + (size_t)tok_s[m0] * DIMM);
    for (int kk = tid >> 4; kk < 128; kk += 16) {      // kk = k/4
        float4 v = xrow[kk];
        int off = ((kk >> 3) * 512) + ((((kk >> 1) & 3) * 16 + m0) * 8) + ((kk & 1) * 4);
        short4 h4, l4;
        h4.x = f2h(v.x); l4.x = f2h((v.x - h2f(h4.x)) * 4096.f);
        h4.y = f2h(v.y); l4.y = f2h((v.y - h2f(h4.y)) * 4096.f);
        h4.z = f2h(v.z); l4.z = f2h((v.z - h2f(h4.z)) * 4096.f);
        h4.w = f2h(v.w); l4.w = f2h((v.w - h2f(h4.w)) * 4096.f);
        *(short4*)(xh + off) = h4;
        *(short4*)(xl + off) = l4;
    }
    __syncthreads();
    int wave = tid >> 6, lane = tid & 63;
    int quad = lane >> 4, lcol = lane & 15;
    f32x4 zero = {0.f, 0.f, 0.f, 0.f};
    f32x4 acc0[8], acc1[8];
    #pragma unroll
    for (int q = 0; q < 8; ++q) { acc0[q] = zero; acc1[q] = zero; }
    const short* whb = w1h + (size_t)e * EDIM * DIMM + (size_t)lane * 8;
    const short* wlb = w1l + (size_t)e * EDIM * DIMM + (size_t)lane * 8;
    for (int ks = 0; ks < 16; ++ks) {
        f16x8 ah = *(const f16x8*)(xh + ks*512 + lane*8);
        f16x8 al = *(const f16x8*)(xl + ks*512 + lane*8);
        #pragma unroll
        for (int q = 0; q < 8; ++q) {
            int nt = by*32 + wave*8 + q;                 // 16-col tile of EDIM
            size_t fo = (size_t)(nt*16 + ks) * 512;      // K/32=16 frags per nt
            f16x8 wh = *(const f16x8*)(whb + fo);
            f16x8 wl = *(const f16x8*)(wlb + fo);
            acc0[q] = __builtin_amdgcn_mfma_f32_16x16x32_f16(ah, wh, acc0[q], 0, 0, 0);
            acc1[q] = __builtin_amdgcn_mfma_f32_16x16x32_f16(al, wh, acc1[q], 0, 0, 0);
            acc1[q] = __builtin_amdgcn_mfma_f32_16x16x32_f16(ah, wl, acc1[q], 0, 0, 0);
        }
    }
    __syncthreads();   // all X-frag reads done; reuse LDS for H-frags
    // ---- gelu + bias, write H as f16 hi/lo' frags (local col hp in [0,512)) ----
    #pragma unroll
    for (int q = 0; q < 8; ++q) {
        int hp = wave*128 + q*16 + lcol;
        float bb = b1[(size_t)e * EDIM + by*512 + hp];
        int obase = ((hp >> 5) * 512) + (((hp >> 3) & 3) * 16) * 8 + (hp & 7);
        #pragma unroll
        for (int r = 0; r < 4; ++r) {
            int mm = quad*4 + r;
            float hv = gelu_exact(acc0[q][r] + acc1[q][r] * (1.f/4096.f) + bb);
            short hh = f2h(hv);
            xh[obase + mm*8] = hh;
            xl[obase + mm*8] = f2h((hv - h2f(hh)) * 4096.f);
        }
    }
    __syncthreads();
    // ---- coalesced copy of this half's frags to global ----
    short* dh = ghhi + (size_t)blockIdx.x * 16384 + (size_t)by * 8192;
    short* dl = ghlo + (size_t)blockIdx.x * 16384 + (size_t)by * 8192;
    const int4* sh = (const int4*)xh;
    const int4* sl = (const int4*)xl;
    #pragma unroll
    for (int j = 0; j < 4; ++j) {                // 16KB / 16B / 256 thr = 4
        ((int4*)dh)[tid + 256*j] = sh[tid + 256*j];
        ((int4*)dl)[tid + 256*j] = sl[tid + 256*j];
    }
}

// ---------------- expert FFN2, f16-pair MFMA, frag-packed W ----------------
__global__ __launch_bounds__(256) void k_effn2(
    const short* __restrict__ ghhi, const short* __restrict__ ghlo,
    const short* __restrict__ w2h, const short* __restrict__ w2l, const float* __restrict__ b2,
    const int2* __restrict__ tiles, const int* __restrict__ ntile,
    const int* __restrict__ eoff, const int* __restrict__ ep_tok, const float* __restrict__ ep_w,
    float* __restrict__ eo) {
    if ((int)blockIdx.x >= *ntile) return;
    int2 tl = tiles[blockIdx.x];
    int e = tl.x, pbase = tl.y;
    int m = min(16, eoff[e+1] - pbase);
    int by = blockIdx.y;                         // d-half of DIMM
    __shared__ int tok_s[16];
    __shared__ float pw_s[16];
    int tid = threadIdx.x;
    if (tid < 16) {
        int ok = tid < m;
        tok_s[tid] = ok ? ep_tok[pbase + tid] : 0;
        pw_s[tid]  = ok ? ep_w[pbase + tid] : 0.f;
    }
    __syncthreads();
    int wave = tid >> 6, lane = tid & 63;
    int quad = lane >> 4, lcol = lane & 15;
    const short* ahb = ghhi + (size_t)blockIdx.x * 16384 + (size_t)lane * 8;
    const short* alb = ghlo + (size_t)blockIdx.x * 16384 + (size_t)lane * 8;
    f32x4 zero = {0.f, 0.f, 0.f, 0.f};
    f32x4 acc0[4], acc1[4];
    #pragma unroll
    for (int q = 0; q < 4; ++q) { acc0[q] = zero; acc1[q] = zero; }
    const short* whb = w2h + (size_t)e * DIMM * EDIM + (size_t)lane * 8;
    const short* wlb = w2l + (size_t)e * DIMM * EDIM + (size_t)lane * 8;
    for (int ks = 0; ks < 32; ++ks) {            // K = 1024
        f16x8 ah = *(const f16x8*)(ahb + ks*512);
        f16x8 al = *(const f16x8*)(alb + ks*512);
        #pragma unroll
        for (int q = 0; q < 4; ++q) {
            int nt = by*16 + wave*4 + q;                 // 16-col tile of DIMM
            size_t fo = (size_t)(nt*32 + ks) * 512;      // K/32=32 frags per nt
            f16x8 wh = *(const f16x8*)(whb + fo);
            f16x8 wl = *(const f16x8*)(wlb + fo);
            acc0[q] = __builtin_amdgcn_mfma_f32_16x16x32_f16(ah, wh, acc0[q], 0, 0, 0);
            acc1[q] = __builtin_amdgcn_mfma_f32_16x16x32_f16(al, wh, acc1[q], 0, 0, 0);
            acc1[q] = __builtin_amdgcn_mfma_f32_16x16x32_f16(ah, wl, acc1[q], 0, 0, 0);
        }
    }
    #pragma unroll
    for (int q = 0; q < 4; ++q) {
        int d = by*256 + wave*64 + q*16 + lcol;
        float bb = b2[(size_t)e * DIMM + d];
        #pragma unroll
        for (int r = 0; r < 4; ++r) {
            int mm = quad*4 + r;
            if (mm < m) {
                float val = (acc0[q][r] + acc1[q][r] * (1.f/4096.f) + bb) * pw_s[mm];
                atomicAdd(&eo[(size_t)tok_s[mm] * DIMM + d], val);
            }
        }
    }
}

// ---------------- micro router logits: mlog = eo @ mrw^T + mrb (4 tokens/block) -------
__global__ __launch_bounds__(384) void k_mlog(
    const float* __restrict__ eo, const float* __restrict__ mw, const float* __restrict__ mb,
    float* __restrict__ mlog) {
    int t0 = blockIdx.x * 4;
    __shared__ float4 es[4][128];
    int tid = threadIdx.x;
    const float4* eo4 = (const float4*)eo;
    for (int q = tid; q < 4*128; q += 384) {
        int i = q >> 7, k = q & 127;
        es[i][k] = eo4[(size_t)(t0 + i) * 128 + k];
    }
    __syncthreads();
    if (tid < NMIC) {
        const float4* wr = (const float4*)(mw + (size_t)tid * DIMM);
        float acc[4] = {0.f, 0.f, 0.f, 0.f};
        for (int kk = 0; kk < 128; ++kk) {
            float4 wv = wr[kk];
            #pragma unroll
            for (int i = 0; i < 4; ++i) acc[i] += dot4(wv, es[i][kk]);
        }
        float bb = mb[tid];
        #pragma unroll
        for (int i = 0; i < 4; ++i) mlog[(size_t)(t0 + i) * NMIC + tid] = acc[i] + bb;
    }
}

// ---------------- micro top-8 softmax + renorm ----------------
__global__ void k_mtop(const float* __restrict__ mlog, int* __restrict__ mtopi,
                       float* __restrict__ mtopp, int* __restrict__ mcnt) {
    int wave = threadIdx.x >> 6, lane = threadIdx.x & 63;
    int t = blockIdx.x * 4 + wave;
    if (t >= T_TOK) return;
    float v[6]; int vi[6];
    #pragma unroll
    for (int j = 0; j < 6; ++j) {
        int n = lane + 64*j;
        vi[j] = n;
        v[j] = (n < NMIC) ? mlog[(size_t)t * NMIC + n] : -1e30f;
    }
    float M = v[0];
    #pragma unroll
    for (int j = 1; j < 6; ++j) M = fmaxf(M, v[j]);
    #pragma unroll
    for (int o = 32; o; o >>= 1) M = fmaxf(M, __shfl_xor(M, o));
    float Z = 0.f;
    #pragma unroll
    for (int j = 0; j < 6; ++j) Z += expf(v[j] - M);
    Z = wave_sum(Z);
    float bk[8]; int bi[8];
    for (int k = 0; k < 8; ++k) {
        float lv = v[0]; int li = vi[0];
        #pragma unroll
        for (int j = 1; j < 6; ++j)
            if (v[j] > lv) { lv = v[j]; li = vi[j]; }
        #pragma unroll
        for (int o = 32; o; o >>= 1) {
            float ov = __shfl_xor(lv, o); int oi = __shfl_xor(li, o);
            if (ov > lv || (ov == lv && oi < li)) { lv = ov; li = oi; }
        }
        bk[k] = expf(lv - M) / Z; bi[k] = li;
        #pragma unroll
        for (int j = 0; j < 6; ++j) if (vi[j] == li) v[j] = -1e30f;
    }
    float s = 0.f;
    #pragma unroll
    for (int k = 0; k < 8; ++k) s += bk[k];
    s += 1e-8f;
    if (lane == 0) {
        for (int k = 0; k < 8; ++k) {
            mtopi[t*8 + k] = bi[k];
            mtopp[t*8 + k] = bk[k] / s;
            atomicAdd(&mcnt[bi[k]], 1);
        }
    }
}

// ---------------- micro FFN1, bf16 MFMA, frag-packed W: H-frags -> global ghbuf -------
__global__ __launch_bounds__(256) void k_mffn1(
    const float* __restrict__ eo, const short* __restrict__ w1f, const float* __restrict__ b1,
    const int2* __restrict__ tiles, const int* __restrict__ ntile,
    const int* __restrict__ moff, const int* __restrict__ mp_tok,
    short* __restrict__ ghbuf) {
    if ((int)blockIdx.x >= *ntile) return;
    int2 tl = tiles[blockIdx.x];
    int mi = tl.x, pbase = tl.y;
    int pm = min(16, moff[mi+1] - pbase);
    int by = blockIdx.y;
    __shared__ __align__(16) short eof[8192];   // 16 tok x 512 bf16 A-frags (16KB)
    __shared__ __align__(16) short hf[2048];    // this block's half of H-frags (4KB)
    __shared__ int tok_s[16];
    int tid = threadIdx.x;
    if (tid < 16) tok_s[tid] = mp_tok[pbase + ((tid < pm) ? tid : 0)];
    __syncthreads();
    int m0 = tid & 15;
    const float4* eorow = (const float4*)(eo + (size_t)tok_s[m0] * DIMM);
    for (int kk = tid >> 4; kk < 128; kk += 16) {      // kk = k/4
        float4 v = eorow[kk];
        int off = ((kk >> 3) * 512) + ((((kk >> 1) & 3) * 16 + m0) * 8) + ((kk & 1) * 4);
        short4 s4; s4.x = f2bf(v.x); s4.y = f2bf(v.y); s4.z = f2bf(v.z); s4.w = f2bf(v.w);
        *(short4*)(eof + off) = s4;
    }
    __syncthreads();
    int wave = tid >> 6, lane = tid & 63;
    int quad = lane >> 4, lcol = lane & 15;
    f32x4 zero = {0.f, 0.f, 0.f, 0.f};
    f32x4 accA[2];
    accA[0] = zero; accA[1] = zero;
    const short* wb = w1f + (size_t)mi * HIDD * DIMM + (size_t)lane * 8;
    for (int ks = 0; ks < 16; ++ks) {
        bf16x8 a = *(bf16x8*)(eof + ks*512 + lane*8);
        #pragma unroll
        for (int q = 0; q < 2; ++q) {
            int nt = by*8 + wave*2 + q;                  // 16-col tile of HIDD
            bf16x8 bfr = *(const bf16x8*)(wb + (size_t)(nt*16 + ks) * 512);
            accA[q] = __builtin_amdgcn_mfma_f32_16x16x32_bf16(a, bfr, accA[q], 0, 0, 0);
        }
    }
    #pragma unroll
    for (int q = 0; q < 2; ++q) {
        int hp = wave*32 + q*16 + lcol;                  // local h in [0,128)
        float bb = b1[(size_t)mi * HIDD + by*128 + hp];
        int obase = ((hp >> 5) * 512) + (((hp >> 3) & 3) * 16) * 8 + (hp & 7);
        #pragma unroll
        for (int r = 0; r < 4; ++r) {
            int mm = quad*4 + r;
            hf[obase + mm*8] = f2bf(gelu_exact(accA[q][r] + bb));
        }
    }
    __syncthreads();
    short* gh = ghbuf + (size_t)blockIdx.x * 4096 + (size_t)by * 2048;
    ((int4*)gh)[tid] = ((const int4*)hf)[tid];          // 256 x 16B = 4KB
}

// ---------------- micro FFN2, bf16 MFMA, frag-packed W: Y -> global ybuf --------------
__global__ __launch_bounds__(256) void k_mffn2(
    const short* __restrict__ ghbuf, const short* __restrict__ w2f, const float* __restrict__ b2,
    const int2* __restrict__ tiles, const int* __restrict__ ntile, const int* __restrict__ moff,
    float* __restrict__ ybuf) {
    if ((int)blockIdx.x >= *ntile) return;
    int2 tl = tiles[blockIdx.x];
    int mi = tl.x, pbase = tl.y;
    int pm = min(16, moff[mi+1] - pbase);
    int by = blockIdx.y;
    int tid = threadIdx.x, wave = tid >> 6, lane = tid & 63;
    int quad = lane >> 4, lcol = lane & 15;
    const short* gh = ghbuf + (size_t)blockIdx.x * 4096 + (size_t)lane * 8;
    f32x4 zero = {0.f, 0.f, 0.f, 0.f};
    f32x4 accB[4];
    #pragma unroll
    for (int q = 0; q < 4; ++q) accB[q] = zero;
    const short* wb = w2f + (size_t)mi * DIMM * HIDD + (size_t)lane * 8;
    for (int ks = 0; ks < 8; ++ks) {
        bf16x8 a = *(const bf16x8*)(gh + ks*512);
        #pragma unroll
        for (int q = 0; q < 4; ++q) {
            int nt = by*16 + wave*4 + q;                 // 16-col tile of DIMM
            bf16x8 bfr = *(const bf16x8*)(wb + (size_t)(nt*8 + ks) * 512);
            accB[q] = __builtin_amdgcn_mfma_f32_16x16x32_bf16(a, bfr, accB[q], 0, 0, 0);
        }
    }
    #pragma unroll
    for (int q = 0; q < 4; ++q) {
        int d = by*256 + wave*64 + q*16 + lcol;
        float bb = b2[(size_t)mi * DIMM + d];
        #pragma unroll
        for (int r = 0; r < 4; ++r) {
            int mm = quad*4 + r;
            if (mm < pm) ybuf[(size_t)(pbase + mm) * DIMM + d] = accB[q][r] + bb;
        }
    }
}

// ---------------- per-pair LayerNorm(eo + Y), weighted accumulate into mo -------------
__global__ __launch_bounds__(256) void k_mln(
    const float* __restrict__ ybuf, const float* __restrict__ eo,
    const float* __restrict__ g, const float* __restrict__ beta,
    const int* __restrict__ mp_tok, const float* __restrict__ mp_w,
    const int* __restrict__ mp_mi, float* __restrict__ mo) {
    int wave = threadIdx.x >> 6, lane = threadIdx.x & 63;
    int p = blockIdx.x * 4 + wave;                 // total pairs = 8192 exactly
    int t = mp_tok[p];
    int mi = mp_mi[p];
    float pw = mp_w[p];
    const float* yr = ybuf + (size_t)p * DIMM;
    const float* er = eo + (size_t)t * DIMM;
    float vv[8];
    float sum = 0.f;
    #pragma unroll
    for (int j = 0; j < 8; ++j) {
        int d = lane + 64*j;
        vv[j] = yr[d] + er[d];
        sum += vv[j];
    }
    sum = wave_sum(sum);
    float mu = sum * (1.f/512.f);
    float var = 0.f;
    #pragma unroll
    for (int j = 0; j < 8; ++j) { float d0 = vv[j] - mu; var += d0*d0; }
    var = wave_sum(var) * (1.f/512.f);
    float rstd = rsqrtf(var + 1e-5f);
    #pragma unroll
    for (int j = 0; j < 8; ++j) {
        int d = lane + 64*j;
        float nj = (vv[j] - mu) * rstd * g[(size_t)mi * DIMM + d] + beta[(size_t)mi * DIMM + d];
        atomicAdd(&mo[(size_t)t * DIMM + d], pw * nj);
    }
}

// ---------------- final LN over eo + 0.1*mo ----------------
__global__ void k_final(const float* __restrict__ eo, const float* __restrict__ mo,
                        const float* __restrict__ g, const float* __restrict__ b,
                        float* __restrict__ out) {
    int wave = threadIdx.x >> 6, lane = threadIdx.x & 63;
    int t = blockIdx.x * 4 + wave;
    if (t >= T_TOK) return;
    float vv[8];
    float sum = 0.f;
    #pragma unroll
    for (int j = 0; j < 8; ++j) {
        int d = lane + 64*j;
        vv[j] = eo[(size_t)t * DIMM + d] + 0.1f * mo[(size_t)t * DIMM + d];
        sum += vv[j];
    }
    sum = wave_sum(sum);
    float mu = sum * (1.f/512.f);
    float var = 0.f;
    #pragma unroll
    for (int j = 0; j < 8; ++j) { float d0 = vv[j] - mu; var += d0*d0; }
    var = wave_sum(var) * (1.f/512.f);
    float rstd = rsqrtf(var + 1e-5f);
    #pragma unroll
    for (int j = 0; j < 8; ++j) {
        int d = lane + 64*j;
        out[(size_t)t * DIMM + d] = (vv[j] - mu) * rstd * g[d] + b[d];
    }
}

extern "C" void kernel_launch(void* const* d_in, const int* in_sizes, int n_in,
                              void* d_out, int out_size, void* d_ws, size_t ws_size,
                              hipStream_t stream) {
    const float* x    = (const float*)d_in[0];
    const float* rw   = (const float*)d_in[1];
    const float* rb   = (const float*)d_in[2];
    const float* ew1  = (const float*)d_in[3];
    const float* eb1  = (const float*)d_in[4];
    const float* ew2  = (const float*)d_in[5];
    const float* eb2  = (const float*)d_in[6];
    const float* mrw  = (const float*)d_in[7];
    const float* mrb  = (const float*)d_in[8];
    const float* mw1  = (const float*)d_in[9];
    const float* mb1  = (const float*)d_in[10];
    const float* mw2  = (const float*)d_in[11];
    const float* mb2  = (const float*)d_in[12];
    const float* mg   = (const float*)d_in[13];
    const float* mbeta= (const float*)d_in[14];
    const float* ng   = (const float*)d_in[15];
    const float* nb   = (const float*)d_in[16];
    float* out = (float*)d_out;

    char* w = (char*)d_ws;
    auto alloc = [&](size_t bytes) -> char* {
        char* p = w;
        w += (bytes + 255) & ~(size_t)255;
        return p;
    };
    const size_t WELEM = (size_t)NEXP * EDIM * DIMM;          // 4,194,304
    const size_t MELEM = (size_t)NMIC * HIDD * DIMM;          // 42,598,400
    float* eo    = (float*)alloc((size_t)T_TOK * DIMM * 4);   // 2 MB
    float* mo    = (float*)alloc((size_t)T_TOK * DIMM * 4);   // 2 MB (contiguous with eo)
    // bufA (16.8 MB): expert W1 hi|lo frags (k_effn1); later ybuf (k_mffn2 -> k_mln)
    short* bufA  = (short*)alloc(WELEM * 2 * 2);
    short* w1h   = bufA;
    short* w1l   = bufA + WELEM;
    float* ybuf  = (float*)bufA;                              // 8192*512*4 = 16.8 MB exactly
    // bufB (85.2 MB): expert W2 hi|lo frags -> micro W1 bf16 frags -> micro W2 bf16 frags
    short* bufB  = (short*)alloc(MELEM * 2);
    short* w2h   = bufB;
    short* w2l   = bufB + WELEM;
    short* mwf   = bufB;                                      // micro weight frags (time-shared)
    // gfrag (8.9 MB): expert H hi|lo frags (effn1->effn2); later micro ghbuf (mffn1->mffn2)
    short* gfrag = (short*)alloc((size_t)E16TILES * 16384 * 2 * 2);
    short* ehhi  = gfrag;
    short* ehlo  = gfrag + (size_t)E16TILES * 16384;
    short* ghbuf = gfrag;                                     // 840*4096*2B = 6.9 MB <= 8.9
    float* mlog  = (float*)alloc((size_t)T_TOK * NMIC * 4);   // 1.3 MB
    float* ewts  = (float*)alloc(2048 * 4);
    float* mtopp = (float*)alloc(8192 * 4);
    float* ep_w  = (float*)alloc(2048 * 4);
    float* mp_w  = (float*)alloc(8192 * 4);
    int*   eidx  = (int*)alloc(2048 * 4);
    int*   mtopi = (int*)alloc(8192 * 4);
    int*   cnts  = (int*)alloc((NEXP + NMIC) * 4);            // ecnt | mcnt contiguous
    int*   ecnt  = cnts;
    int*   mcnt  = cnts + NEXP;
    int*   eoff  = (int*)alloc((NEXP + 1) * 4);
    int*   ecur  = (int*)alloc(NEXP * 4);
    int*   moff  = (int*)alloc((NMIC + 1) * 4);
    int*   mcur  = (int*)alloc(NMIC * 4);
    int2*  etile = (int2*)alloc(E16TILES * 8);
    int2*  mtile = (int2*)alloc(MTILES * 8);
    int*   entile= (int*)alloc(4);
    int*   mntile= (int*)alloc(4);
    int*   ep_tok= (int*)alloc(2048 * 4);
    int*   mp_tok= (int*)alloc(8192 * 4);
    int*   ep_mi = (int*)alloc(2048 * 4);                     // unused downstream
    int*   mp_mi = (int*)alloc(8192 * 4);

    hipMemsetAsync(eo, 0, (size_t)2 * T_TOK * DIMM * 4, stream);   // eo + mo
    hipMemsetAsync(cnts, 0, (NEXP + NMIC) * 4, stream);

    // ---- expert weight packing (f16 hi/lo frag-major) ----
    k_packhl<<<512, 256, 0, stream>>>(ew1, w1h, w1l, 512, 512, 1);   // 8192 rows, K=512
    k_packhl<<<512, 256, 0, stream>>>(ew2, w2h, w2l, 1024, 512, 2);  // 4096 rows, K=1024

    k_router <<<T_TOK/4, 256, 0, stream>>>(x, rw, rb, eidx, ewts, ecnt);
    k_scan   <<<1, 512, 0, stream>>>(ecnt, NEXP, 16, eoff, ecur, etile, entile);
    k_scatter<<<(T_TOK*2 + 255)/256, 256, 0, stream>>>(eidx, ewts, T_TOK*2, 2, ecur, ep_tok, ep_w, ep_mi);
    k_effn1  <<<dim3(E16TILES, 2, 1), 256, 0, stream>>>(x, w1h, w1l, eb1, etile, entile, eoff, ep_tok, ehhi, ehlo);
    k_effn2  <<<dim3(E16TILES, 2, 1), 256, 0, stream>>>(ehhi, ehlo, w2h, w2l, eb2, etile, entile, eoff, ep_tok, ep_w, eo);
    k_mlog   <<<T_TOK/4, 384, 0, stream>>>(eo, mrw, mrb, mlog);
    k_mtop   <<<T_TOK/4, 256, 0, stream>>>(mlog, mtopi, mtopp, mcnt);
    k_scan   <<<1, 512, 0, stream>>>(mcnt, NMIC, 16, moff, mcur, mtile, mntile);
    k_scatter<<<(T_TOK*8 + 255)/256, 256, 0, stream>>>(mtopi, mtopp, T_TOK*8, 8, mcur, mp_tok, mp_w, mp_mi);
    // ---- micro W1 bf16 frag pack into bufB (expert frags dead after k_effn2) ----
    k_packbf <<<5200, 256, 0, stream>>>(mw1, mwf, 512, 512, 1);       // 83200 rows, K=512
    k_mffn1  <<<dim3(MTILES, 2, 1), 256, 0, stream>>>(eo, mwf, mb1, mtile, mntile, moff, mp_tok, ghbuf);
    // ---- micro W2 bf16 frag pack into bufB (W1 frags dead after k_mffn1) ----
    k_packbf <<<10400, 256, 0, stream>>>(mw2, mwf, 256, 256, 1);      // 166400 rows, K=256
    k_mffn2  <<<dim3(MTILES, 2, 1), 256, 0, stream>>>(ghbuf, mwf, mb2, mtile, mntile, moff, ybuf);
    k_mln    <<<NPAIR_M/4, 256, 0, stream>>>(ybuf, eo, mg, mbeta, mp_tok, mp_w, mp_mi, mo);
    k_final  <<<T_TOK/4, 256, 0, stream>>>(eo, mo, ng, nb, out);
}